// Round 1
// baseline (492.994 us; speedup 1.0000x reference)
//
#include <hip/hip_runtime.h>
#include <math.h>

// Problem constants (from reference setup_inputs)
constexpr int B_  = 2;
constexpr int NS_ = 2048;
constexpr int NT_ = 32768;
constexpr int K_  = 32;
#define RADIUS_F 0.08f

constexpr int TPB = 256;                       // 4 waves
constexpr int WAVES = TPB / 64;
constexpr int TGT_PER_WAVE = 8;
constexpr int TGT_PER_BLOCK = WAVES * TGT_PER_WAVE;      // 32
constexpr int BLOCKS_PER_BATCH = NT_ / TGT_PER_BLOCK;    // 1024
constexpr int NCHUNK = NS_ / 64;                         // 32

// Output layout: tuple concatenated flat, in return order (all as float)
constexpr long long SZ_PATCH = (long long)B_ * NT_ * K_ * 3;
constexpr long long SZ_IDX   = (long long)B_ * NT_ * K_ * 2;
constexpr long long SZ_SIZE  = (long long)B_ * NT_;
constexpr long long SZ_RAD   = B_;
constexpr long long SZ_DIST  = (long long)B_ * NT_ * K_;
constexpr long long O_PATCH = 0;
constexpr long long O_IDX   = O_PATCH + SZ_PATCH;
constexpr long long O_SIZE  = O_IDX + SZ_IDX;
constexpr long long O_RAD   = O_SIZE + SZ_SIZE;
constexpr long long O_DIST  = O_RAD + SZ_RAD;
constexpr long long O_WD    = O_DIST + SZ_DIST;

__global__ __launch_bounds__(TPB) void group_points_kernel(
    const float* __restrict__ src,
    const float* __restrict__ tgt,
    const float* __restrict__ sden,
    float* __restrict__ out)
{
    // LDS: source points with |s|^2 in .w, plus source densities
    __shared__ float4 s_sp[NS_];
    __shared__ float  s_sd[NS_];

    const int tid  = threadIdx.x;
    const int lane = tid & 63;
    const int wav  = tid >> 6;
    const int b    = blockIdx.x / BLOCKS_PER_BATCH;
    const int tile = blockIdx.x % BLOCKS_PER_BATCH;

    // Stage this batch's source points (+precomputed |s|^2) and densities.
    for (int j = tid; j < NS_; j += TPB) {
        const float* p = src + ((long long)b * NS_ + j) * 3;
        float x = p[0], y = p[1], z = p[2];
        // match XLA: sum(s*s) = (x*x + y*y) + z*z, no fma contraction
        float r1 = __fadd_rn(__fadd_rn(__fmul_rn(x, x), __fmul_rn(y, y)), __fmul_rn(z, z));
        s_sp[j] = make_float4(x, y, z, r1);
        s_sd[j] = sden[(long long)b * NS_ + j];
    }
    __syncthreads();

    if (blockIdx.x == 0 && tid == 0) {
        out[O_RAD + 0] = RADIUS_F;   // rad output (B,1,1) of 0.08
        out[O_RAD + 1] = RADIUS_F;
    }

    const float dd = RADIUS_F + 1e-6f;          // rad + 1e-6 divisor
    const float r2 = __fmul_rn(RADIUS_F, RADIUS_F);  // rad**2 in fp32

    for (int g = 0; g < TGT_PER_WAVE; ++g) {
        const int t = tile * TGT_PER_BLOCK + wav * TGT_PER_WAVE + g;
        const long long tb = (long long)b * NT_ + t;
        const float tx = tgt[tb * 3 + 0];
        const float ty = tgt[tb * 3 + 1];
        const float tz = tgt[tb * 3 + 2];
        const float r0 = __fadd_rn(__fadd_rn(__fmul_rn(tx, tx), __fmul_rn(ty, ty)), __fmul_rn(tz, tz));

        // ---- chunk 0: distances for sources 0..63, full bitonic sort across wave ----
        float lv; int li;
        {
            float4 sp = s_sp[lane];
            float dot = __fadd_rn(__fadd_rn(__fmul_rn(tx, sp.x), __fmul_rn(ty, sp.y)), __fmul_rn(tz, sp.z));
            lv = __fadd_rn(__fsub_rn(r0, __fmul_rn(2.0f, dot)), sp.w);
            li = lane;
        }
        #pragma unroll
        for (int k = 2; k <= 64; k <<= 1) {
            #pragma unroll
            for (int j = k >> 1; j > 0; j >>= 1) {
                float pv = __shfl_xor(lv, j);
                int   pi = __shfl_xor(li, j);
                bool takeMin = (((lane & k) == 0) == ((lane & j) == 0));
                bool mineSmaller = (lv < pv) || (lv == pv && li < pi);
                bool keep = (takeMin == mineSmaller);
                lv = keep ? lv : pv;
                li = keep ? li : pi;
            }
        }
        // lanes 0..63 now hold the 64 candidates ascending; threshold = 32nd smallest
        float T = __shfl(lv, 31);

        // ---- chunks 1..31: ballot-filtered sorted insertion ----
        for (int c = 1; c < NCHUNK; ++c) {
            const int j = (c << 6) + lane;
            float4 sp = s_sp[j];
            float dot = __fadd_rn(__fadd_rn(__fmul_rn(tx, sp.x), __fmul_rn(ty, sp.y)), __fmul_rn(tz, sp.z));
            float d = __fadd_rn(__fsub_rn(r0, __fmul_rn(2.0f, dot)), sp.w);
            unsigned long long m = __ballot(d < T);
            while (m) {                       // wave-uniform loop
                const int sl = __ffsll((unsigned long long)m) - 1;
                m &= (m - 1);
                const float v = __shfl(d, sl);     // broadcast candidate
                if (v < T) {                        // uniform re-check vs updated T
                    const int vi = (c << 6) + sl;
                    float pv = __shfl_up(lv, 1);
                    int   pi = __shfl_up(li, 1);
                    if (lv > v) {                   // lanes past insertion point shift up
                        bool at = (lane == 0) || (pv <= v);
                        lv = at ? v : pv;
                        li = at ? vi : pi;
                    }
                    T = __shfl(lv, 31);
                }
            }
        }

        // ---- outputs: lanes 0..31 hold sorted top-32 (sq_pd, src index) ----
        const bool isTop = (lane < K_);
        const float sq = lv;
        const bool valid = isTop && (r2 >= sq);
        float4 sp = make_float4(0.f, 0.f, 0.f, 0.f);
        float dvv = 0.f;
        if (valid) { sp = s_sp[li]; dvv = s_sd[li]; }
        const float tsx = tx / dd, tsy = ty / dd, tsz = tz / dd;

        if (isTop) {
            const long long pb = tb * K_ + lane;
            // patches = where(valid, src/dd, 0) - tgt/dd  (invalid slots get -tgt_s)
            out[O_PATCH + pb * 3 + 0] = (valid ? sp.x / dd : 0.0f) - tsx;
            out[O_PATCH + pb * 3 + 1] = (valid ? sp.y / dd : 0.0f) - tsy;
            out[O_PATCH + pb * 3 + 2] = (valid ? sp.z / dd : 0.0f) - tsz;
            out[O_IDX + pb * 2 + 0] = (float)b;
            out[O_IDX + pb * 2 + 1] = valid ? (float)li : -1.0f;
            // dist output uses true sq_pd regardless of validity
            out[O_DIST + tb * K_ + lane] = sqrtf(fmaxf(sq, 1e-9f)) / dd;
        }

        const unsigned long long vb = __ballot(valid);
        float ds = dvv;                        // density sum over valid slots
        #pragma unroll
        for (int o = 32; o > 0; o >>= 1) ds += __shfl_xor(ds, o);
        if (lane == 0) {
            const int vc = __popcll(vb);
            out[O_SIZE + tb] = (float)vc;                 // patches_size
            out[O_WD + tb] = ds / (float)(K_ - vc);       // sum(density)/mask_cnt
        }
    }
}

extern "C" void kernel_launch(void* const* d_in, const int* in_sizes, int n_in,
                              void* d_out, int out_size, void* d_ws, size_t ws_size,
                              hipStream_t stream) {
    const float* src  = (const float*)d_in[0];   // (B,Ns,3)
    const float* tgt  = (const float*)d_in[1];   // (B,Nt,3)
    const float* sden = (const float*)d_in[2];   // (B,Ns,1)
    // d_in[3] = target_density: only feeds a dead value in the reference
    float* out = (float*)d_out;

    dim3 grid(B_ * BLOCKS_PER_BATCH);            // 2048 blocks
    group_points_kernel<<<grid, TPB, 0, stream>>>(src, tgt, sden, out);
}

// Round 2
// 259.199 us; speedup vs baseline: 1.9020x; 1.9020x over previous
//
#include <hip/hip_runtime.h>
#include <math.h>

// Problem constants (from reference setup_inputs)
constexpr int B_  = 2;
constexpr int NS_ = 2048;
constexpr int NT_ = 32768;
constexpr int K_  = 32;
#define RADIUS_F 0.08f

constexpr int TPB = 512;                                 // 8 waves
constexpr int WAVES = TPB / 64;
constexpr int TGT_PER_WAVE = 8;
constexpr int TGT_PER_BLOCK = WAVES * TGT_PER_WAVE;      // 64
constexpr int BLOCKS_PER_BATCH = NT_ / TGT_PER_BLOCK;    // 512
constexpr int NCHUNK = NS_ / 64;                         // 32

// Output layout: tuple concatenated flat, in return order (all float)
constexpr long long SZ_PATCH = (long long)B_ * NT_ * K_ * 3;
constexpr long long SZ_IDX   = (long long)B_ * NT_ * K_ * 2;
constexpr long long SZ_SIZE  = (long long)B_ * NT_;
constexpr long long SZ_RAD   = B_;
constexpr long long SZ_DIST  = (long long)B_ * NT_ * K_;
constexpr long long O_PATCH = 0;
constexpr long long O_IDX   = O_PATCH + SZ_PATCH;
constexpr long long O_SIZE  = O_IDX + SZ_IDX;
constexpr long long O_RAD   = O_SIZE + SZ_SIZE;
constexpr long long O_DIST  = O_RAD + SZ_RAD;
constexpr long long O_WD    = O_DIST + SZ_DIST;

__device__ __forceinline__ float readlane_f(float v, int l) {
    return __int_as_float(__builtin_amdgcn_readlane(__float_as_int(v), l));
}
__device__ __forceinline__ float bperm_f(int addr, float v) {
    return __int_as_float(__builtin_amdgcn_ds_bpermute(addr, __float_as_int(v)));
}

__global__ __launch_bounds__(TPB, 8) void group_points_kernel(
    const float* __restrict__ src,
    const float* __restrict__ tgt,
    const float* __restrict__ sden,
    float* __restrict__ out)
{
    // LDS: source points with |s|^2 in .w  (32 KiB -> 4 blocks/CU, 100% occ cap)
    __shared__ float4 s_sp[NS_];

    const int tid  = threadIdx.x;
    const int lane = tid & 63;
    const int wav  = tid >> 6;
    const int b    = blockIdx.x / BLOCKS_PER_BATCH;
    const int tile = blockIdx.x % BLOCKS_PER_BATCH;

    for (int j = tid; j < NS_; j += TPB) {
        const float* p = src + ((long long)b * NS_ + j) * 3;
        float x = p[0], y = p[1], z = p[2];
        // match XLA: r1 = (x*x + y*y) + z*z, no fma contraction
        float r1 = __fadd_rn(__fadd_rn(__fmul_rn(x, x), __fmul_rn(y, y)), __fmul_rn(z, z));
        s_sp[j] = make_float4(x, y, z, r1);
    }
    if (blockIdx.x == 0 && tid == 0) {
        out[O_RAD + 0] = RADIUS_F;
        out[O_RAD + 1] = RADIUS_F;
    }
    __syncthreads();

    const float dd    = RADIUS_F + 1e-6f;
    const float invdd = 1.0f / dd;                           // compile-time const
    const float r2    = __fmul_rn(RADIUS_F, RADIUS_F);
    const int   addrup = (lane - 1) << 2;                    // bpermute addr: lv[lane-1]
    const bool  l0 = (lane == 0);

    for (int g = 0; g < TGT_PER_WAVE; ++g) {
        const int t = tile * TGT_PER_BLOCK + wav * TGT_PER_WAVE + g;
        const long long tb = (long long)b * NT_ + t;
        const float tx = tgt[tb * 3 + 0];
        const float ty = tgt[tb * 3 + 1];
        const float tz = tgt[tb * 3 + 2];
        const float r0 = __fadd_rn(__fadd_rn(__fmul_rn(tx, tx), __fmul_rn(ty, ty)), __fmul_rn(tz, tz));

        // recorded within-radius candidates (lane-indexed slots, value+index)
        float rv = 0.f; int ri = 0; int nv = 0;

        // ---- chunk 0: 64 distances, record radius hits, bitonic sort values ----
        float lv;
        {
            float4 sp = s_sp[lane];
            float dot = __fadd_rn(__fadd_rn(__fmul_rn(tx, sp.x), __fmul_rn(ty, sp.y)), __fmul_rn(tz, sp.z));
            float d0 = __fadd_rn(__fsub_rn(r0, __fmul_rn(2.0f, dot)), sp.w);
            unsigned long long mr = __ballot(r2 >= d0);
            if (mr) {
                while (mr) {
                    int sl = __builtin_ctzll(mr); mr &= mr - 1;
                    float v = readlane_f(d0, sl);
                    if (lane == nv) { rv = v; ri = sl; }
                    ++nv;
                }
            }
            lv = d0;
        }
        #pragma unroll
        for (int k = 2; k <= 64; k <<= 1) {
            #pragma unroll
            for (int j = k >> 1; j > 0; j >>= 1) {
                float pv = __shfl_xor(lv, j);
                bool takeMin = (((lane & k) == 0) == ((lane & j) == 0));
                bool smaller = (lv < pv);
                lv = (takeMin == smaller) ? lv : pv;
            }
        }
        float T = readlane_f(lv, 31);      // 32nd smallest so far

        // ---- chunks 1..31: ballot filter + value-only sorted insertion ----
        for (int c = 1; c < NCHUNK; ++c) {
            float4 sp = s_sp[(c << 6) + lane];
            float dot = __fadd_rn(__fadd_rn(__fmul_rn(tx, sp.x), __fmul_rn(ty, sp.y)), __fmul_rn(tz, sp.z));
            float d = __fadd_rn(__fsub_rn(r0, __fmul_rn(2.0f, dot)), sp.w);

            unsigned long long mr = __ballot(r2 >= d);
            if (mr) {                       // rare: within-radius candidates
                const int base = c << 6;
                while (mr) {
                    int sl = __builtin_ctzll(mr); mr &= mr - 1;
                    float v = readlane_f(d, sl);
                    if (lane == nv) { rv = v; ri = base + sl; }
                    ++nv;
                }
            }

            unsigned long long m = __ballot(d < T);
            while (m) {                     // wave-uniform loop
                int sl = __builtin_ctzll(m); m &= m - 1;
                float v  = readlane_f(d, sl);
                float pv = bperm_f(addrup, lv);          // lv[lane-1]
                bool at = l0 || (pv <= v);
                float cand = at ? v : pv;
                if (lv > v) lv = cand;                   // lanes past insert pos shift up
            }
            T = readlane_f(lv, 31);         // refresh threshold once per chunk
        }

        // ---- epilogue: lanes 0..31 hold sorted top-32 values ----
        int vflag = 0; int vidx = -1; float dsum = 0.f; int vcnt = 0;
        const int nvc = (nv > 64) ? 64 : nv;
        for (int s = 0; s < nvc; ++s) {
            float vr = readlane_f(rv, s);
            int   ir = __builtin_amdgcn_readlane(ri, s);
            int rank = (int)__popcll(__ballot(lv < vr));
            for (int q = 0; q < s; ++q)                  // ties: earlier index first
                rank += (readlane_f(rv, q) == vr) ? 1 : 0;
            if (rank < K_) {
                dsum += sden[(long long)b * NS_ + ir];   // uniform scalar load
                ++vcnt;
                if (lane == rank) { vflag = 1; vidx = ir; }
            }
        }

        float px = 0.f, py = 0.f, pz = 0.f;
        if (vflag) { float4 spv = s_sp[vidx]; px = spv.x; py = spv.y; pz = spv.z; }
        const float tsx = tx * invdd, tsy = ty * invdd, tsz = tz * invdd;

        if (lane < K_) {
            const long long pb = tb * K_ + lane;
            out[O_PATCH + pb * 3 + 0] = (vflag ? px * invdd : 0.0f) - tsx;
            out[O_PATCH + pb * 3 + 1] = (vflag ? py * invdd : 0.0f) - tsy;
            out[O_PATCH + pb * 3 + 2] = (vflag ? pz * invdd : 0.0f) - tsz;
            out[O_IDX + pb * 2 + 0] = (float)b;
            out[O_IDX + pb * 2 + 1] = (float)vidx;       // -1 when invalid
            out[O_DIST + tb * K_ + lane] = sqrtf(fmaxf(lv, 1e-9f)) * invdd;
        }
        if (l0) {
            out[O_SIZE + tb] = (float)vcnt;
            out[O_WD + tb]   = dsum / (float)(K_ - vcnt);
        }
    }
}

extern "C" void kernel_launch(void* const* d_in, const int* in_sizes, int n_in,
                              void* d_out, int out_size, void* d_ws, size_t ws_size,
                              hipStream_t stream) {
    const float* src  = (const float*)d_in[0];   // (B,Ns,3)
    const float* tgt  = (const float*)d_in[1];   // (B,Nt,3)
    const float* sden = (const float*)d_in[2];   // (B,Ns,1)
    // d_in[3] = target_density: feeds only a dead value in the reference
    float* out = (float*)d_out;

    dim3 grid(B_ * BLOCKS_PER_BATCH);            // 1024 blocks, one generation
    group_points_kernel<<<grid, TPB, 0, stream>>>(src, tgt, sden, out);
}

// Round 4
// 216.012 us; speedup vs baseline: 2.2823x; 1.1999x over previous
//
#include <hip/hip_runtime.h>
#include <math.h>

// Problem constants (from reference setup_inputs)
constexpr int B_  = 2;
constexpr int NS_ = 2048;
constexpr int NT_ = 32768;
constexpr int K_  = 32;
#define RADIUS_F 0.08f

constexpr int TPB = 512;                                 // 8 waves
constexpr int WAVES = TPB / 64;
constexpr int TGT_PER_WAVE = 8;
constexpr int TGT_PER_BLOCK = WAVES * TGT_PER_WAVE;      // 64
constexpr int BLOCKS_PER_BATCH = NT_ / TGT_PER_BLOCK;    // 512
constexpr int NCHUNK = NS_ / 64;                         // 32

// Output layout: tuple concatenated flat, in return order (all float)
constexpr long long SZ_PATCH = (long long)B_ * NT_ * K_ * 3;
constexpr long long SZ_IDX   = (long long)B_ * NT_ * K_ * 2;
constexpr long long SZ_SIZE  = (long long)B_ * NT_;
constexpr long long SZ_RAD   = B_;
constexpr long long SZ_DIST  = (long long)B_ * NT_ * K_;
constexpr long long O_PATCH = 0;
constexpr long long O_IDX   = O_PATCH + SZ_PATCH;
constexpr long long O_SIZE  = O_IDX + SZ_IDX;
constexpr long long O_RAD   = O_SIZE + SZ_SIZE;
constexpr long long O_DIST  = O_RAD + SZ_RAD;
constexpr long long O_WD    = O_DIST + SZ_DIST;

// Compile-time bitonic take-min direction mask for stage (k,j)
constexpr unsigned long long tm_mask(int k, int j) {
    unsigned long long m = 0;
    for (int l = 0; l < 64; ++l)
        if (((l & k) == 0) == ((l & j) == 0)) m |= 1ull << l;
    return m;
}

__device__ __forceinline__ float readlane_f(float v, int l) {
    return __int_as_float(__builtin_amdgcn_readlane(__float_as_int(v), l));
}
__device__ __forceinline__ float bperm_f(int addr, float v) {
    return __int_as_float(__builtin_amdgcn_ds_bpermute(addr, __float_as_int(v)));
}
// lane i <- lane i-1 across the whole wave; lane 0 <- 0 (wave_shr:1, bound_ctrl)
__device__ __forceinline__ float shr1_f(float v) {
    return __int_as_float(__builtin_amdgcn_update_dpp(0, __float_as_int(v),
                                                      0x138, 0xF, 0xF, true));
}
// sorted insert: lv' = med3(lv[lane-1], v, lv); v broadcast in SGPR (float bits)
__device__ __forceinline__ float med3_vsv(float pv, int vbits, float lv) {
    float r;
    asm("v_med3_f32 %0, %1, %2, %3" : "=v"(r) : "v"(pv), "s"(vbits), "v"(lv));
    return r;
}
// lv = keep-bit ? lv : pv  (cndmask with SGPR-pair mask)
__device__ __forceinline__ void cnds(float& lv, float pv, unsigned long long keep) {
    float r;
    asm("v_cndmask_b32 %0, %2, %1, %3" : "=v"(r) : "v"(lv), "v"(pv), "s"(keep));
    lv = r;
}
__device__ __forceinline__ float dist_f(float tx, float ty, float tz, float r0, float4 sp) {
    // match XLA: r0 - 2*dot + r1, mul/add chain, no fma contraction
    float dot = __fadd_rn(__fadd_rn(__fmul_rn(tx, sp.x), __fmul_rn(ty, sp.y)), __fmul_rn(tz, sp.z));
    return __fadd_rn(__fsub_rn(r0, __fmul_rn(2.0f, dot)), sp.w);
}

// one bitonic stage on LV with xor-partner address AJ, direction mask tm_mask(K,J)
#define BSTG(LV, AJ, K, J) { \
    constexpr unsigned long long tm_ = tm_mask(K, J); \
    float pv_ = bperm_f(AJ, LV); \
    unsigned long long sm_ = __ballot((LV) < pv_); \
    cnds(LV, pv_, ~(sm_ ^ tm_)); \
}
#define BSTG2(AJ, K, J) { BSTG(lv0, AJ, K, J) BSTG(lv1, AJ, K, J) }

// ballot-filtered serial insert; records radius hits (d<=r2 as signed-int cmp on
// float bits -- valid since r2>0; any final-valid element satisfies d<T at scan time)
#define INS_LOOP(D, LV, T, RV, RI, NV, BASE) { \
    unsigned long long m_ = __ballot((D) < (T)); \
    while (m_) { \
        const int sl_ = (int)__builtin_ctzll(m_); m_ &= m_ - 1; \
        const int vb_ = __builtin_amdgcn_readlane(__float_as_int(D), sl_); \
        if (vb_ <= r2i) { \
            if (lane == (NV)) { RV = __int_as_float(vb_); RI = (BASE) + sl_; } \
            ++(NV); \
        } \
        LV = med3_vsv(shr1_f(LV), vb_, LV); \
    } \
}

__device__ __forceinline__ void epilogue(
    float* __restrict__ out, const float* __restrict__ sden, const float4* ssp,
    int b, long long tb, int lane,
    float lv, float rv, int ri, int nv,
    float tx, float ty, float tz)
{
    const float invdd = 1.0f / (RADIUS_F + 1e-6f);
    int vflag = 0; int vidx = -1; float dsum = 0.f; int vcnt = 0;
    const long long sdb = (long long)b * NS_;
    const int nvc = (nv > 64) ? 64 : nv;
    for (int s = 0; s < nvc; ++s) {
        float vr = readlane_f(rv, s);
        int   ir = __builtin_amdgcn_readlane(ri, s);
        int rank = (int)__popcll(__ballot(lv < vr));
        for (int q = 0; q < s; ++q)                  // ties: earlier index first
            rank += (readlane_f(rv, q) == vr) ? 1 : 0;
        if (rank < K_) {
            dsum += sden[sdb + ir];
            ++vcnt;
            if (lane == rank) { vflag = 1; vidx = ir; }
        }
    }
    float px = 0.f, py = 0.f, pz = 0.f;
    if (vflag) { float4 spv = ssp[vidx]; px = spv.x; py = spv.y; pz = spv.z; }
    const float tsx = tx * invdd, tsy = ty * invdd, tsz = tz * invdd;
    if (lane < K_) {
        const long long pb = tb * K_ + lane;
        float3 p3;
        p3.x = (vflag ? px * invdd : 0.0f) - tsx;
        p3.y = (vflag ? py * invdd : 0.0f) - tsy;
        p3.z = (vflag ? pz * invdd : 0.0f) - tsz;
        *reinterpret_cast<float3*>(&out[O_PATCH + pb * 3]) = p3;
        float2 ix;
        ix.x = (float)b;
        ix.y = (float)vidx;                          // -1 when invalid
        *reinterpret_cast<float2*>(&out[O_IDX + pb * 2]) = ix;
        out[O_DIST + tb * K_ + lane] = sqrtf(fmaxf(lv, 1e-9f)) * invdd;
    }
    if (lane == 0) {
        out[O_SIZE + tb] = (float)vcnt;
        out[O_WD + tb]   = dsum / (float)(K_ - vcnt);
    }
}

__global__ __launch_bounds__(TPB, 8) void group_points_kernel(
    const float* __restrict__ src,
    const float* __restrict__ tgt,
    const float* __restrict__ sden,
    float* __restrict__ out)
{
    __shared__ float4 s_sp[NS_];                     // 32 KiB

    const int tid  = threadIdx.x;
    const int lane = tid & 63;
    const int wav  = tid >> 6;
    const int b    = blockIdx.x / BLOCKS_PER_BATCH;
    const int tile = blockIdx.x % BLOCKS_PER_BATCH;

    for (int j = tid; j < NS_; j += TPB) {
        const float* p = src + ((long long)b * NS_ + j) * 3;
        float x = p[0], y = p[1], z = p[2];
        float r1 = __fadd_rn(__fadd_rn(__fmul_rn(x, x), __fmul_rn(y, y)), __fmul_rn(z, z));
        s_sp[j] = make_float4(x, y, z, r1);
    }
    if (blockIdx.x == 0 && tid == 0) {
        out[O_RAD + 0] = RADIUS_F;
        out[O_RAD + 1] = RADIUS_F;
    }
    __syncthreads();

    const float r2f = __fmul_rn(RADIUS_F, RADIUS_F);
    const int   r2i = __float_as_int(r2f);
    // precomputed xor-partner bpermute addresses
    const int a1  = (lane ^ 1)  << 2;
    const int a2  = (lane ^ 2)  << 2;
    const int a4  = (lane ^ 4)  << 2;
    const int a8  = (lane ^ 8)  << 2;
    const int a16 = (lane ^ 16) << 2;
    const int a32 = (lane ^ 32) << 2;

    for (int gp = 0; gp < TGT_PER_WAVE / 2; ++gp) {
        const int t0 = tile * TGT_PER_BLOCK + wav * TGT_PER_WAVE + 2 * gp;
        const long long tb0 = (long long)b * NT_ + t0;
        const float* tp = tgt + tb0 * 3;
        const float tx0 = tp[0], ty0 = tp[1], tz0 = tp[2];
        const float tx1 = tp[3], ty1 = tp[4], tz1 = tp[5];
        const float r00 = __fadd_rn(__fadd_rn(__fmul_rn(tx0, tx0), __fmul_rn(ty0, ty0)), __fmul_rn(tz0, tz0));
        const float r01 = __fadd_rn(__fadd_rn(__fmul_rn(tx1, tx1), __fmul_rn(ty1, ty1)), __fmul_rn(tz1, tz1));

        float rv0 = 0.f, rv1 = 0.f; int ri0 = 0, ri1 = 0; int nv0 = 0, nv1 = 0;

        // ---- chunk 0: distances, radius-record, bitonic seed sort (values only) ----
        float lv0, lv1;
        {
            float4 sp = s_sp[lane];
            float d0 = dist_f(tx0, ty0, tz0, r00, sp);
            float d1 = dist_f(tx1, ty1, tz1, r01, sp);
            unsigned long long mr0 = __ballot(r2f >= d0);
            while (mr0) {
                int sl = (int)__builtin_ctzll(mr0); mr0 &= mr0 - 1;
                float v = readlane_f(d0, sl);
                if (lane == nv0) { rv0 = v; ri0 = sl; }
                ++nv0;
            }
            unsigned long long mr1 = __ballot(r2f >= d1);
            while (mr1) {
                int sl = (int)__builtin_ctzll(mr1); mr1 &= mr1 - 1;
                float v = readlane_f(d1, sl);
                if (lane == nv1) { rv1 = v; ri1 = sl; }
                ++nv1;
            }
            lv0 = d0; lv1 = d1;
        }
        BSTG2(a1, 2, 1)
        BSTG2(a2, 4, 2)  BSTG2(a1, 4, 1)
        BSTG2(a4, 8, 4)  BSTG2(a2, 8, 2)  BSTG2(a1, 8, 1)
        BSTG2(a8, 16, 8) BSTG2(a4, 16, 4) BSTG2(a2, 16, 2) BSTG2(a1, 16, 1)
        BSTG2(a16, 32, 16) BSTG2(a8, 32, 8) BSTG2(a4, 32, 4) BSTG2(a2, 32, 2) BSTG2(a1, 32, 1)
        BSTG2(a32, 64, 32) BSTG2(a16, 64, 16) BSTG2(a8, 64, 8) BSTG2(a4, 64, 4) BSTG2(a2, 64, 2) BSTG2(a1, 64, 1)
        float T0 = readlane_f(lv0, 31);
        float T1 = readlane_f(lv1, 31);

        // ---- chunks 1..31: shared LDS load, two independent insert pipelines ----
        for (int c = 1; c < NCHUNK; ++c) {
            float4 sp = s_sp[(c << 6) + lane];
            float d0 = dist_f(tx0, ty0, tz0, r00, sp);
            float d1 = dist_f(tx1, ty1, tz1, r01, sp);
            const int base = c << 6;
            INS_LOOP(d0, lv0, T0, rv0, ri0, nv0, base)
            INS_LOOP(d1, lv1, T1, rv1, ri1, nv1, base)
            T0 = readlane_f(lv0, 31);
            T1 = readlane_f(lv1, 31);
        }

        epilogue(out, sden, s_sp, b, tb0,     lane, lv0, rv0, ri0, nv0, tx0, ty0, tz0);
        epilogue(out, sden, s_sp, b, tb0 + 1, lane, lv1, rv1, ri1, nv1, tx1, ty1, tz1);
    }
}

extern "C" void kernel_launch(void* const* d_in, const int* in_sizes, int n_in,
                              void* d_out, int out_size, void* d_ws, size_t ws_size,
                              hipStream_t stream) {
    const float* src  = (const float*)d_in[0];   // (B,Ns,3)
    const float* tgt  = (const float*)d_in[1];   // (B,Nt,3)
    const float* sden = (const float*)d_in[2];   // (B,Ns,1)
    // d_in[3] = target_density: feeds only a dead value in the reference
    float* out = (float*)d_out;

    dim3 grid(B_ * BLOCKS_PER_BATCH);            // 1024 blocks
    group_points_kernel<<<grid, TPB, 0, stream>>>(src, tgt, sden, out);
}

// Round 5
// 209.331 us; speedup vs baseline: 2.3551x; 1.0319x over previous
//
#include <hip/hip_runtime.h>
#include <math.h>

// Problem constants (from reference setup_inputs)
constexpr int B_  = 2;
constexpr int NS_ = 2048;
constexpr int NT_ = 32768;
constexpr int K_  = 32;
#define RADIUS_F 0.08f

constexpr int TPB = 512;                                 // 8 waves
constexpr int TGT_PER_WAVE = 8;
constexpr int TGT_PER_BLOCK = 8 * TGT_PER_WAVE;          // 64
constexpr int BLOCKS_PER_BATCH = NT_ / TGT_PER_BLOCK;    // 512
constexpr int NCHUNK = NS_ / 64;                         // 32

// Output layout: tuple concatenated flat, in return order (all float)
constexpr long long SZ_PATCH = (long long)B_ * NT_ * K_ * 3;
constexpr long long SZ_IDX   = (long long)B_ * NT_ * K_ * 2;
constexpr long long SZ_SIZE  = (long long)B_ * NT_;
constexpr long long SZ_RAD   = B_;
constexpr long long SZ_DIST  = (long long)B_ * NT_ * K_;
constexpr long long O_PATCH = 0;
constexpr long long O_IDX   = O_PATCH + SZ_PATCH;
constexpr long long O_SIZE  = O_IDX + SZ_IDX;
constexpr long long O_RAD   = O_SIZE + SZ_SIZE;
constexpr long long O_DIST  = O_RAD + SZ_RAD;
constexpr long long O_WD    = O_DIST + SZ_DIST;

// Compile-time bitonic take-min direction mask for stage (k,j)
constexpr unsigned long long tm_mask(int k, int j) {
    unsigned long long m = 0;
    for (int l = 0; l < 64; ++l)
        if (((l & k) == 0) == ((l & j) == 0)) m |= 1ull << l;
    return m;
}

__device__ __forceinline__ float readlane_f(float v, int l) {
    return __int_as_float(__builtin_amdgcn_readlane(__float_as_int(v), l));
}
__device__ __forceinline__ float bperm_f(int addr, float v) {
    return __int_as_float(__builtin_amdgcn_ds_bpermute(addr, __float_as_int(v)));
}
// lane i <- lane i-1 across the whole wave; lane 0 <- 0 (wave_shr:1, bound_ctrl)
__device__ __forceinline__ float shr1_f(float v) {
    return __int_as_float(__builtin_amdgcn_update_dpp(0, __float_as_int(v),
                                                      0x138, 0xF, 0xF, true));
}
// sorted single insert: lv' = med3(lv[lane-1], v, lv); v broadcast bits in SGPR
__device__ __forceinline__ float med3_vsv(float pv, int vbits, float lv) {
    float r;
    asm("v_med3_f32 %0, %1, %2, %3" : "=v"(r) : "v"(pv), "s"(vbits), "v"(lv));
    return r;
}
// max(p, sgpr-broadcast w)
__device__ __forceinline__ float maxs_f(float p, int wbits) {
    float r;
    asm("v_max_f32 %0, %1, %2" : "=v"(r) : "s"(wbits), "v"(p));
    return r;
}
__device__ __forceinline__ float min3_f(float a, float b, float c) {
    float r;
    asm("v_min3_f32 %0, %1, %2, %3" : "=v"(r) : "v"(a), "v"(b), "v"(c));
    return r;
}
// lv = keep-bit ? lv : pv  (cndmask with SGPR-pair mask)
__device__ __forceinline__ void cnds(float& lv, float pv, unsigned long long keep) {
    float r;
    asm("v_cndmask_b32 %0, %2, %1, %3" : "=v"(r) : "v"(lv), "v"(pv), "s"(keep));
    lv = r;
}
__device__ __forceinline__ float dist_f(float tx, float ty, float tz, float r0, float4 sp) {
    // match XLA: r0 - 2*dot + r1, mul/add chain, no fma contraction
    float dot = __fadd_rn(__fadd_rn(__fmul_rn(tx, sp.x), __fmul_rn(ty, sp.y)), __fmul_rn(tz, sp.z));
    return __fadd_rn(__fsub_rn(r0, __fmul_rn(2.0f, dot)), sp.w);
}

// one bitonic stage on LV with xor-partner address AJ, direction mask tm_mask(K,J)
#define BSTG(LV, AJ, K, J) { \
    constexpr unsigned long long tm_ = tm_mask(K, J); \
    float pv_ = bperm_f(AJ, LV); \
    unsigned long long sm_ = __ballot((LV) < pv_); \
    cnds(LV, pv_, ~(sm_ ^ tm_)); \
}
// one stage applied to all 8 seed lists (interleaved for ILP)
#define S8(AJ, K, J) { BSTG(sa0, AJ, K, J) BSTG(sa1, AJ, K, J) BSTG(sa2, AJ, K, J) BSTG(sa3, AJ, K, J) \
                       BSTG(sb0, AJ, K, J) BSTG(sb1, AJ, K, J) BSTG(sb2, AJ, K, J) BSTG(sb3, AJ, K, J) }
// bitonic-merge cleanup stage applied to the 4 merged lists (ascending: k=128)
#define C4(AJ, J) { BSTG(sa0, AJ, 128, J) BSTG(sa1, AJ, 128, J) BSTG(sa2, AJ, 128, J) BSTG(sa3, AJ, 128, J) }

// record within-radius hits of D (rare), in index order
#define REC(D, RV, RI, NV, BASE) { \
    unsigned long long mr_ = __ballot(r2f >= (D)); \
    while (mr_) { \
        int sl_ = (int)__builtin_ctzll(mr_); mr_ &= mr_ - 1; \
        float v_ = readlane_f(D, sl_); \
        if (lane == (NV)) { RV = v_; RI = (BASE) + sl_; } \
        ++(NV); \
    } \
}

// ballot-filtered insertion, two candidates per iteration:
// lv' = min3(lv, max(lv[-1], w1), max(lv[-2], w2)) with w1 <= w2
#define INS2(D, LV, T) { \
    unsigned long long m_ = __ballot((D) < (T)); \
    while (m_) { \
        const int sl1_ = (int)__builtin_ctzll(m_); m_ &= m_ - 1; \
        const int b1_ = __builtin_amdgcn_readlane(__float_as_int(D), sl1_); \
        if (m_) { \
            const int sl2_ = (int)__builtin_ctzll(m_); m_ &= m_ - 1; \
            const int b2_ = __builtin_amdgcn_readlane(__float_as_int(D), sl2_); \
            const int w1_ = (b1_ < b2_) ? b1_ : b2_; \
            const int w2_ = (b1_ < b2_) ? b2_ : b1_; \
            float p1_ = shr1_f(LV); \
            float p2_ = shr1_f(p1_); \
            float t1_ = maxs_f(p1_, w1_); \
            float t2_ = maxs_f(p2_, w2_); \
            LV = min3_f(LV, t1_, t2_); \
        } else { \
            LV = med3_vsv(shr1_f(LV), b1_, LV); \
        } \
    } \
}

__device__ __forceinline__ void epilogue(
    float* __restrict__ out, const float* __restrict__ sden, const float4* ssp,
    int b, long long tb, int lane,
    float lv, float rv, int ri, int nv,
    float tx, float ty, float tz)
{
    const float invdd = 1.0f / (RADIUS_F + 1e-6f);
    int vflag = 0; int vidx = -1; float dsum = 0.f; int vcnt = 0;
    const long long sdb = (long long)b * NS_;
    const int nvc = (nv > 64) ? 64 : nv;
    for (int s = 0; s < nvc; ++s) {
        float vr = readlane_f(rv, s);
        int   ir = __builtin_amdgcn_readlane(ri, s);
        int rank = (int)__popcll(__ballot(lv < vr));
        for (int q = 0; q < s; ++q)                  // ties: earlier index first
            rank += (readlane_f(rv, q) == vr) ? 1 : 0;
        if (rank < K_) {
            dsum += sden[sdb + ir];
            ++vcnt;
            if (lane == rank) { vflag = 1; vidx = ir; }
        }
    }
    float px = 0.f, py = 0.f, pz = 0.f;
    if (vflag) { float4 spv = ssp[vidx]; px = spv.x; py = spv.y; pz = spv.z; }
    const float tsx = tx * invdd, tsy = ty * invdd, tsz = tz * invdd;
    if (lane < K_) {
        const long long pb = tb * K_ + lane;
        float3 p3;
        p3.x = (vflag ? px * invdd : 0.0f) - tsx;
        p3.y = (vflag ? py * invdd : 0.0f) - tsy;
        p3.z = (vflag ? pz * invdd : 0.0f) - tsz;
        *reinterpret_cast<float3*>(&out[O_PATCH + pb * 3]) = p3;
        float2 ix;
        ix.x = (float)b;
        ix.y = (float)vidx;                          // -1 when invalid
        *reinterpret_cast<float2*>(&out[O_IDX + pb * 2]) = ix;
        out[O_DIST + tb * K_ + lane] = sqrtf(fmaxf(lv, 1e-9f)) * invdd;
    }
    if (lane == 0) {
        out[O_SIZE + tb] = (float)vcnt;
        out[O_WD + tb]   = dsum / (float)(K_ - vcnt);
    }
}

__global__ __launch_bounds__(TPB, 8) void group_points_kernel(
    const float* __restrict__ src,
    const float* __restrict__ tgt,
    const float* __restrict__ sden,
    float* __restrict__ out)
{
    __shared__ float4 s_sp[NS_];                     // 32 KiB

    const int tid  = threadIdx.x;
    const int lane = tid & 63;
    const int wav  = tid >> 6;
    const int b    = blockIdx.x / BLOCKS_PER_BATCH;
    const int tile = blockIdx.x % BLOCKS_PER_BATCH;

    for (int j = tid; j < NS_; j += TPB) {
        const float* p = src + ((long long)b * NS_ + j) * 3;
        float x = p[0], y = p[1], z = p[2];
        float r1 = __fadd_rn(__fadd_rn(__fmul_rn(x, x), __fmul_rn(y, y)), __fmul_rn(z, z));
        s_sp[j] = make_float4(x, y, z, r1);
    }
    if (blockIdx.x == 0 && tid == 0) {
        out[O_RAD + 0] = RADIUS_F;
        out[O_RAD + 1] = RADIUS_F;
    }
    __syncthreads();

    const float r2f = __fmul_rn(RADIUS_F, RADIUS_F);
    // precomputed xor-partner / reverse bpermute addresses
    const int a1  = (lane ^ 1)  << 2;
    const int a2  = (lane ^ 2)  << 2;
    const int a4  = (lane ^ 4)  << 2;
    const int a8  = (lane ^ 8)  << 2;
    const int a16 = (lane ^ 16) << 2;
    const int a32 = (lane ^ 32) << 2;
    const int arev = (63 - lane) << 2;

    for (int gp = 0; gp < TGT_PER_WAVE / 4; ++gp) {
        const int t0 = tile * TGT_PER_BLOCK + wav * TGT_PER_WAVE + gp * 4;
        const long long tb0 = (long long)b * NT_ + t0;
        const float* tp = tgt + tb0 * 3;
        const float tx0 = tp[0],  ty0 = tp[1],  tz0 = tp[2];
        const float tx1 = tp[3],  ty1 = tp[4],  tz1 = tp[5];
        const float tx2 = tp[6],  ty2 = tp[7],  tz2 = tp[8];
        const float tx3 = tp[9],  ty3 = tp[10], tz3 = tp[11];
        const float r00 = __fadd_rn(__fadd_rn(__fmul_rn(tx0, tx0), __fmul_rn(ty0, ty0)), __fmul_rn(tz0, tz0));
        const float r01 = __fadd_rn(__fadd_rn(__fmul_rn(tx1, tx1), __fmul_rn(ty1, ty1)), __fmul_rn(tz1, tz1));
        const float r02 = __fadd_rn(__fadd_rn(__fmul_rn(tx2, tx2), __fmul_rn(ty2, ty2)), __fmul_rn(tz2, tz2));
        const float r03 = __fadd_rn(__fadd_rn(__fmul_rn(tx3, tx3), __fmul_rn(ty3, ty3)), __fmul_rn(tz3, tz3));

        float rv0 = 0.f, rv1 = 0.f, rv2 = 0.f, rv3 = 0.f;
        int   ri0 = 0,   ri1 = 0,   ri2 = 0,   ri3 = 0;
        int   nv0 = 0,   nv1 = 0,   nv2 = 0,   nv3 = 0;

        // ---- seed: chunks 0+1 -> 128-element sorted seed, keep low 64 ----
        float4 sp0 = s_sp[lane];
        float4 sp1 = s_sp[64 + lane];
        float sa0 = dist_f(tx0, ty0, tz0, r00, sp0);
        float sa1 = dist_f(tx1, ty1, tz1, r01, sp0);
        float sa2 = dist_f(tx2, ty2, tz2, r02, sp0);
        float sa3 = dist_f(tx3, ty3, tz3, r03, sp0);
        float sb0 = dist_f(tx0, ty0, tz0, r00, sp1);
        float sb1 = dist_f(tx1, ty1, tz1, r01, sp1);
        float sb2 = dist_f(tx2, ty2, tz2, r02, sp1);
        float sb3 = dist_f(tx3, ty3, tz3, r03, sp1);
        // radius-record (per target: chunk0 then chunk1 = index order)
        REC(sa0, rv0, ri0, nv0, 0)  REC(sb0, rv0, ri0, nv0, 64)
        REC(sa1, rv1, ri1, nv1, 0)  REC(sb1, rv1, ri1, nv1, 64)
        REC(sa2, rv2, ri2, nv2, 0)  REC(sb2, rv2, ri2, nv2, 64)
        REC(sa3, rv3, ri3, nv3, 0)  REC(sb3, rv3, ri3, nv3, 64)
        // sort all 8 lists ascending (stage-interleaved)
        S8(a1, 2, 1)
        S8(a2, 4, 2)   S8(a1, 4, 1)
        S8(a4, 8, 4)   S8(a2, 8, 2)   S8(a1, 8, 1)
        S8(a8, 16, 8)  S8(a4, 16, 4)  S8(a2, 16, 2)  S8(a1, 16, 1)
        S8(a16, 32, 16) S8(a8, 32, 8) S8(a4, 32, 4)  S8(a2, 32, 2)  S8(a1, 32, 1)
        S8(a32, 64, 32) S8(a16, 64, 16) S8(a8, 64, 8) S8(a4, 64, 4) S8(a2, 64, 2) S8(a1, 64, 1)
        // merge: low half of (sa asc, sb desc) is bitonic; 6-stage cleanup
        sa0 = fminf(sa0, bperm_f(arev, sb0));
        sa1 = fminf(sa1, bperm_f(arev, sb1));
        sa2 = fminf(sa2, bperm_f(arev, sb2));
        sa3 = fminf(sa3, bperm_f(arev, sb3));
        C4(a32, 32) C4(a16, 16) C4(a8, 8) C4(a4, 4) C4(a2, 2) C4(a1, 1)
        float T0 = readlane_f(sa0, 31);
        float T1 = readlane_f(sa1, 31);
        float T2 = readlane_f(sa2, 31);
        float T3 = readlane_f(sa3, 31);

        // ---- scan chunks 2..31: 4 independent insert pipelines ----
        for (int c = 2; c < NCHUNK; ++c) {
            float4 sp = s_sp[(c << 6) + lane];
            float d0 = dist_f(tx0, ty0, tz0, r00, sp);
            float d1 = dist_f(tx1, ty1, tz1, r01, sp);
            float d2 = dist_f(tx2, ty2, tz2, r02, sp);
            float d3 = dist_f(tx3, ty3, tz3, r03, sp);
            const int base = c << 6;
            REC(d0, rv0, ri0, nv0, base)
            REC(d1, rv1, ri1, nv1, base)
            REC(d2, rv2, ri2, nv2, base)
            REC(d3, rv3, ri3, nv3, base)
            INS2(d0, sa0, T0)  T0 = readlane_f(sa0, 31);
            INS2(d1, sa1, T1)  T1 = readlane_f(sa1, 31);
            INS2(d2, sa2, T2)  T2 = readlane_f(sa2, 31);
            INS2(d3, sa3, T3)  T3 = readlane_f(sa3, 31);
        }

        epilogue(out, sden, s_sp, b, tb0,     lane, sa0, rv0, ri0, nv0, tx0, ty0, tz0);
        epilogue(out, sden, s_sp, b, tb0 + 1, lane, sa1, rv1, ri1, nv1, tx1, ty1, tz1);
        epilogue(out, sden, s_sp, b, tb0 + 2, lane, sa2, rv2, ri2, nv2, tx2, ty2, tz2);
        epilogue(out, sden, s_sp, b, tb0 + 3, lane, sa3, rv3, ri3, nv3, tx3, ty3, tz3);
    }
}

extern "C" void kernel_launch(void* const* d_in, const int* in_sizes, int n_in,
                              void* d_out, int out_size, void* d_ws, size_t ws_size,
                              hipStream_t stream) {
    const float* src  = (const float*)d_in[0];   // (B,Ns,3)
    const float* tgt  = (const float*)d_in[1];   // (B,Nt,3)
    const float* sden = (const float*)d_in[2];   // (B,Ns,1)
    // d_in[3] = target_density: feeds only a dead value in the reference
    float* out = (float*)d_out;

    dim3 grid(B_ * BLOCKS_PER_BATCH);            // 1024 blocks
    group_points_kernel<<<grid, TPB, 0, stream>>>(src, tgt, sden, out);
}